// Round 3
// baseline (1310.602 us; speedup 1.0000x reference)
//
#include <hip/hip_runtime.h>
#include <cstdint>

// ---------------------------------------------------------------------------
// q[256][262144], s[512][262144] fp32.
// rank by d2 ~ s2[n] - 2*(q.s)[m][n]; per-row top-10 -> threshold -> row mask
// out = q * mask[row]
// K1: split-K bf16-split GEMM (qh*sh + qh*sl + ql*sh), 4 blocks/CU for TLP
// K2: reduce partials + per-row top-10 (tie -> lower index)
// K3: threshold + mask; K4: masked copy
// ---------------------------------------------------------------------------

typedef __attribute__((ext_vector_type(8))) __bf16 bf16x8;
typedef __attribute__((ext_vector_type(4))) float f32x4;
typedef __attribute__((ext_vector_type(4))) unsigned int uintx4;

#define KTOT 262144
#define MQ 256
#define NS 512
#define BM 128
#define BN 128
#define BK 32
#define KSPLIT 128
#define KC (KTOT / KSPLIT)      // 2048
#define NSTEPS (KC / BK)        // 64
#define LSTRIDE 20              // uints per LDS row = 40 bf16 (padded from 32)

__device__ inline unsigned int cvtpk_bf16(float a, float b) {
    unsigned int r;
    asm("v_cvt_pk_bf16_f32 %0, %1, %2" : "=v"(r) : "v"(a), "v"(b));
    return r; // r[15:0]=bf16(a), r[31:16]=bf16(b)
}

__device__ inline void split2(float a, float b, unsigned int& h, unsigned int& l) {
    h = cvtpk_bf16(a, b);
    float ra = a - __uint_as_float(h << 16);          // exact (Sterbenz)
    float rb = b - __uint_as_float(h & 0xFFFF0000u);  // exact
    l = cvtpk_bf16(ra, rb);
}

__device__ inline void split8(const float4& x, const float4& y, uintx4& h, uintx4& l) {
    unsigned int h0, h1, h2, h3, l0, l1, l2, l3;
    split2(x.x, x.y, h0, l0);
    split2(x.z, x.w, h1, l1);
    split2(y.x, y.y, h2, l2);
    split2(y.z, y.w, h3, l3);
    h = (uintx4){h0, h1, h2, h3};
    l = (uintx4){l0, l1, l2, l3};
}

// ---------------------------------------------------------------------------
// K1: grid = KSPLIT*8 (chunk-major: the 8 sibling tiles of a chunk co-run ->
// L3 reuse of the chunk slices). block = 256 threads (4 waves, 2x2 wave grid,
// wave tile 64x64). LDS 40 KB -> 4 blocks/CU; VGPR capped for 4 waves/SIMD.
// ---------------------------------------------------------------------------
__global__ __launch_bounds__(256, 4)
void k1_gemm(const float* __restrict__ Q, const float* __restrict__ S,
             float* __restrict__ Ppart, float* __restrict__ s2part)
{
    __shared__ __align__(16) unsigned int Ah[BM * LSTRIDE];
    __shared__ __align__(16) unsigned int Al[BM * LSTRIDE];
    __shared__ __align__(16) unsigned int Bh[BN * LSTRIDE];
    __shared__ __align__(16) unsigned int Bl[BN * LSTRIDE];

    const int tid   = threadIdx.x;
    const int bid   = blockIdx.x;
    const int chunk = bid >> 3;
    const int mtile = (bid >> 2) & 1;
    const int ntile = bid & 3;
    const long k0   = (long)chunk * KC;

    // staging: 2 threads/row, 16 floats each, for both A and B
    const int st_row = tid >> 1;
    const int st_kh  = (tid & 1) * 8;   // uint offset within LDS row

    const float4* ap = (const float4*)(Q + (long)(mtile * BM + st_row) * KTOT + k0 + (long)st_kh * 2);
    const float4* bp = (const float4*)(S + (long)(ntile * BN + st_row) * KTOT + k0 + (long)st_kh * 2);

    const int lane = tid & 63;
    const int wave = tid >> 6;
    const int wm = wave >> 1;   // 0..1
    const int wn = wave & 1;    // 0..1
    const int lr = lane & 15;
    const int lk = lane >> 4;

    int aoff[4], boff[4];
#pragma unroll
    for (int f = 0; f < 4; ++f) {
        aoff[f] = (wm * 64 + f * 16 + lr) * LSTRIDE + lk * 4;
        boff[f] = (wn * 64 + f * 16 + lr) * LSTRIDE + lk * 4;
    }

    f32x4 acc[4][4];
#pragma unroll
    for (int i = 0; i < 4; ++i)
#pragma unroll
        for (int j = 0; j < 4; ++j)
            acc[i][j] = (f32x4){0.f, 0.f, 0.f, 0.f};

    float ssq = 0.f;
    const int wr = st_row * LSTRIDE + st_kh;

    // prefetch step 0
    float4 pa0 = ap[0], pa1 = ap[1], pa2 = ap[2], pa3 = ap[3];
    float4 pb0 = bp[0], pb1 = bp[1], pb2 = bp[2], pb3 = bp[3];

    for (int s = 0; s < NSTEPS; ++s) {
        if (s) __syncthreads();   // previous compute done before LDS overwrite
        uintx4 ha0, la0, ha1, la1, hb0, lb0, hb1, lb1;
        split8(pa0, pa1, ha0, la0);
        split8(pa2, pa3, ha1, la1);
        split8(pb0, pb1, hb0, lb0);
        split8(pb2, pb3, hb1, lb1);
        ssq += pb0.x*pb0.x + pb0.y*pb0.y + pb0.z*pb0.z + pb0.w*pb0.w
             + pb1.x*pb1.x + pb1.y*pb1.y + pb1.z*pb1.z + pb1.w*pb1.w
             + pb2.x*pb2.x + pb2.y*pb2.y + pb2.z*pb2.z + pb2.w*pb2.w
             + pb3.x*pb3.x + pb3.y*pb3.y + pb3.z*pb3.z + pb3.w*pb3.w;
        *(uintx4*)&Ah[wr]     = ha0;
        *(uintx4*)&Ah[wr + 4] = ha1;
        *(uintx4*)&Al[wr]     = la0;
        *(uintx4*)&Al[wr + 4] = la1;
        *(uintx4*)&Bh[wr]     = hb0;
        *(uintx4*)&Bh[wr + 4] = hb1;
        *(uintx4*)&Bl[wr]     = lb0;
        *(uintx4*)&Bl[wr + 4] = lb1;
        // issue next-step global loads; latency hides under MFMA phase (+TLP)
        if (s + 1 < NSTEPS) {
            const float4* a2 = ap + (long)(s + 1) * 8;
            const float4* b2 = bp + (long)(s + 1) * 8;
            pa0 = a2[0]; pa1 = a2[1]; pa2 = a2[2]; pa3 = a2[3];
            pb0 = b2[0]; pb1 = b2[1]; pb2 = b2[2]; pb3 = b2[3];
        }
        __syncthreads();

        bf16x8 ah[4], al[4], bh[4], bl[4];
#pragma unroll
        for (int f = 0; f < 4; ++f) {
            ah[f] = *(const bf16x8*)&Ah[aoff[f]];
            al[f] = *(const bf16x8*)&Al[aoff[f]];
            bh[f] = *(const bf16x8*)&Bh[boff[f]];
            bl[f] = *(const bf16x8*)&Bl[boff[f]];
        }
#pragma unroll
        for (int i = 0; i < 4; ++i)
#pragma unroll
            for (int j = 0; j < 4; ++j) {
                acc[i][j] = __builtin_amdgcn_mfma_f32_16x16x32_bf16(ah[i], bh[j], acc[i][j], 0, 0, 0);
                acc[i][j] = __builtin_amdgcn_mfma_f32_16x16x32_bf16(ah[i], bl[j], acc[i][j], 0, 0, 0);
                acc[i][j] = __builtin_amdgcn_mfma_f32_16x16x32_bf16(al[i], bh[j], acc[i][j], 0, 0, 0);
            }
    }

    // s2 partials: 2 stager lanes per B row; only mtile==0 writes
    float s2v = ssq + __shfl_xor(ssq, 1);
    if (mtile == 0 && (tid & 1) == 0)
        s2part[chunk * NS + ntile * BN + st_row] = s2v;

    // write q.s partial tile  (C/D layout: col=lane&15, row=(lane>>4)*4+reg)
    float* op = Ppart + (long)chunk * (MQ * NS);
#pragma unroll
    for (int i = 0; i < 4; ++i)
#pragma unroll
        for (int j = 0; j < 4; ++j) {
            int mb = mtile * BM + wm * 64 + i * 16 + lk * 4;
            int nn = ntile * BN + wn * 64 + j * 16 + lr;
#pragma unroll
            for (int r = 0; r < 4; ++r)
                op[(long)(mb + r) * NS + nn] = acc[i][j][r];
        }
}

// ---------------------------------------------------------------------------
// K2: one block per query row: reduce K-split partials -> d2 row -> top-10
// ---------------------------------------------------------------------------
__global__ __launch_bounds__(256)
void k2_topk(const float* __restrict__ Ppart, const float* __restrict__ s2part,
             int* __restrict__ idxb)
{
    __shared__ float d2s[NS];
    const int m = blockIdx.x;
    const int tid = threadIdx.x;
    for (int nn = tid; nn < NS; nn += 256) {
        float s2 = 0.f, p = 0.f;
        for (int c = 0; c < KSPLIT; ++c) {
            s2 += s2part[c * NS + nn];
            p  += Ppart[(long)c * (MQ * NS) + (long)m * NS + nn];
        }
        d2s[nn] = s2 - 2.f * p;
    }
    __syncthreads();
    if (tid < 64) {
        unsigned long long key[8];
#pragma unroll
        for (int j = 0; j < 8; ++j) {
            int n = tid * 8 + j;
            unsigned int u = __float_as_uint(d2s[n]);
            u = (u >> 31) ? ~u : (u | 0x80000000u);   // total order, ascending
            key[j] = ((unsigned long long)u << 32) | (unsigned int)n;
        }
        for (int it = 0; it < 10; ++it) {
            unsigned long long best = key[0];
#pragma unroll
            for (int j = 1; j < 8; ++j) best = key[j] < best ? key[j] : best;
            for (int d = 1; d < 64; d <<= 1) {
                unsigned long long o = __shfl_xor(best, d);
                best = o < best ? o : best;
            }
            if (tid == 0) idxb[m * 10 + it] = (int)(best & 0xFFFFFFFFu);
#pragma unroll
            for (int j = 0; j < 8; ++j) if (key[j] == best) key[j] = ~0ull;
        }
    }
}

// ---------------------------------------------------------------------------
// K3: losses / best_k / threshold / mask  (integer sums < 2^24 -> exact fp32)
// ---------------------------------------------------------------------------
__global__ __launch_bounds__(256)
void k3_thresh(const int* __restrict__ idxb, float* __restrict__ mask)
{
    __shared__ int colsum[10];
    __shared__ float thr;
    const int tid = threadIdx.x;
    if (tid < 10) {
        int s = 0;
        for (int m = 0; m < MQ; ++m) s += idxb[m * 10 + tid];
        colsum[tid] = s;
    }
    __syncthreads();
    if (tid == 0) {
        float pre = 0.f, best = 3.4e38f;
        for (int k = 1; k <= 10; ++k) {
            pre += (float)colsum[k - 1];
            float loss = pre / (256.0f * (float)k);
            if (loss < best) best = loss;   // first-min == argmin; threshold = losses[best_k]
        }
        thr = best;
    }
    __syncthreads();
    if (tid < MQ) mask[tid] = ((float)idxb[tid * 10] < thr) ? 1.0f : 0.0f;
}

// ---------------------------------------------------------------------------
// K4: out = q * mask[row]   (float4, 2^18 floats per row)
// ---------------------------------------------------------------------------
__global__ __launch_bounds__(256)
void k4_apply(const float* __restrict__ Q, const float* __restrict__ mask,
              float* __restrict__ out)
{
    long i = ((long)blockIdx.x * 256 + threadIdx.x) * 4;
    int row = (int)(i >> 18);
    float4 v = *(const float4*)(Q + i);
    float mm = mask[row];
    v.x *= mm; v.y *= mm; v.z *= mm; v.w *= mm;
    *(float4*)(out + i) = v;
}

extern "C" void kernel_launch(void* const* d_in, const int* in_sizes, int n_in,
                              void* d_out, int out_size, void* d_ws, size_t ws_size,
                              hipStream_t stream)
{
    const float* Q = (const float*)d_in[0];
    const float* S = (const float*)d_in[1];
    float* out = (float*)d_out;

    // scratch inside d_out (overwritten by k4 afterwards); only mask must
    // survive into k4, so it lives in d_ws.
    float* Ppart  = out;                                   // 128*256*512 f32 = 64 MiB
    float* s2part = out + (long)KSPLIT * MQ * NS;          // 128*512 f32
    int*   idxb   = (int*)(s2part + KSPLIT * NS);          // 256*10 int
    float* mask   = (float*)d_ws;                          // 256 f32

    hipLaunchKernelGGL(k1_gemm,  dim3(KSPLIT * 8), dim3(256), 0, stream, Q, S, Ppart, s2part);
    hipLaunchKernelGGL(k2_topk,  dim3(MQ),         dim3(256), 0, stream, Ppart, s2part, idxb);
    hipLaunchKernelGGL(k3_thresh,dim3(1),          dim3(256), 0, stream, idxb, mask);
    hipLaunchKernelGGL(k4_apply, dim3(65536),      dim3(256), 0, stream, Q, mask, out);
}

// Round 4
// 427.445 us; speedup vs baseline: 3.0661x; 3.0661x over previous
//
#include <hip/hip_runtime.h>
#include <cstdint>

// ---------------------------------------------------------------------------
// q[256][262144], s[512][262144] fp32.
// rank by d2 ~ s2[n] - 2*(q.s)[m][n]; per-row top-10 -> threshold -> row mask
// out = q * mask[row]
// K1: split-K bf16-split GEMM (qh*sh + qh*sl + ql*sh), LDS double-buffered
//     (1 barrier/step) + 2-deep register prefetch. R2 geometry (known-good
//     regs: no spills at launch_bounds(512,2)).
// K2: reduce partials + per-row top-10; K3: threshold+mask; K4: masked copy
// ---------------------------------------------------------------------------

typedef __attribute__((ext_vector_type(8))) __bf16 bf16x8;
typedef __attribute__((ext_vector_type(4))) float f32x4;
typedef __attribute__((ext_vector_type(4))) unsigned int uintx4;

#define KTOT 262144
#define MQ 256
#define NS 512
#define BM 256
#define BN 128
#define BK 32
#define KSPLIT 64
#define KC (KTOT / KSPLIT)      // 4096
#define NSTEPS (KC / BK)        // 128
#define LSTRIDE 20              // uints per LDS row (40 bf16; 80B stride -> 2-way max)
#define AHo 0
#define ALo (BM * LSTRIDE)      // 5120
#define BHo (2 * BM * LSTRIDE)  // 10240
#define BLo (2 * BM * LSTRIDE + BN * LSTRIDE)  // 12800
#define HALF (2 * BM * LSTRIDE + 2 * BN * LSTRIDE) // 15360 uints = 60 KiB

__device__ inline unsigned int cvtpk_bf16(float a, float b) {
    unsigned int r;
    asm("v_cvt_pk_bf16_f32 %0, %1, %2" : "=v"(r) : "v"(a), "v"(b));
    return r; // r[15:0]=bf16(a), r[31:16]=bf16(b)
}

__device__ inline void split2(float a, float b, unsigned int& h, unsigned int& l) {
    h = cvtpk_bf16(a, b);
    float ra = a - __uint_as_float(h << 16);          // exact (Sterbenz)
    float rb = b - __uint_as_float(h & 0xFFFF0000u);  // exact
    l = cvtpk_bf16(ra, rb);
}

__device__ inline void split8(const float4& x, const float4& y, uintx4& h, uintx4& l) {
    unsigned int h0, h1, h2, h3, l0, l1, l2, l3;
    split2(x.x, x.y, h0, l0);
    split2(x.z, x.w, h1, l1);
    split2(y.x, y.y, h2, l2);
    split2(y.z, y.w, h3, l3);
    h = (uintx4){h0, h1, h2, h3};
    l = (uintx4){l0, l1, l2, l3};
}

__device__ inline void split_store(unsigned int* __restrict__ buf,
    const float4& a0, const float4& a1, const float4& a2, const float4& a3,
    const float4& b0, const float4& b1, int awr, int bwr, float& ssq)
{
    uintx4 h0, l0, h1, l1, hb, lb;
    split8(a0, a1, h0, l0);
    split8(a2, a3, h1, l1);
    split8(b0, b1, hb, lb);
    ssq += b0.x*b0.x + b0.y*b0.y + b0.z*b0.z + b0.w*b0.w
         + b1.x*b1.x + b1.y*b1.y + b1.z*b1.z + b1.w*b1.w;
    *(uintx4*)&buf[AHo + awr]     = h0;
    *(uintx4*)&buf[AHo + awr + 4] = h1;
    *(uintx4*)&buf[ALo + awr]     = l0;
    *(uintx4*)&buf[ALo + awr + 4] = l1;
    *(uintx4*)&buf[BHo + bwr]     = hb;
    *(uintx4*)&buf[BLo + bwr]     = lb;
}

__device__ inline void mfma_phase(const unsigned int* __restrict__ buf,
                                  const int* __restrict__ aoff,
                                  const int* __restrict__ boff,
                                  f32x4 (&acc)[4][4])
{
    bf16x8 ah[4], al[4], bh[4], bl[4];
#pragma unroll
    for (int f = 0; f < 4; ++f) {
        ah[f] = *(const bf16x8*)&buf[AHo + aoff[f]];
        al[f] = *(const bf16x8*)&buf[ALo + aoff[f]];
        bh[f] = *(const bf16x8*)&buf[BHo + boff[f]];
        bl[f] = *(const bf16x8*)&buf[BLo + boff[f]];
    }
#pragma unroll
    for (int i = 0; i < 4; ++i)
#pragma unroll
        for (int j = 0; j < 4; ++j) {
            acc[i][j] = __builtin_amdgcn_mfma_f32_16x16x32_bf16(ah[i], bh[j], acc[i][j], 0, 0, 0);
            acc[i][j] = __builtin_amdgcn_mfma_f32_16x16x32_bf16(ah[i], bl[j], acc[i][j], 0, 0, 0);
            acc[i][j] = __builtin_amdgcn_mfma_f32_16x16x32_bf16(al[i], bh[j], acc[i][j], 0, 0, 0);
        }
}

// named-register prefetch slot load (no runtime-indexed arrays -> stays in regs)
#define LOADSLOT(Sa0, Sa1, Sa2, Sa3, Sb0, Sb1, STEP)                     \
    { const float4* a_ = ap + (long)(STEP) * 8;                          \
      const float4* b_ = bp + (long)(STEP) * 8;                          \
      Sa0 = a_[0]; Sa1 = a_[1]; Sa2 = a_[2]; Sa3 = a_[3];                \
      Sb0 = b_[0]; Sb1 = b_[1]; }

// ---------------------------------------------------------------------------
// K1: grid = KSPLIT*4 (chunk-major -> L3 dedups the 4x Q-slice reuse).
// block = 512 threads (8 waves, 4x2 wave grid, wave tile 64x64).
// ---------------------------------------------------------------------------
__global__ __launch_bounds__(512, 2)
void k1_gemm(const float* __restrict__ Q, const float* __restrict__ S,
             float* __restrict__ Ppart, float* __restrict__ s2part)
{
    __shared__ __align__(16) unsigned int Lds[2 * HALF];   // 120 KiB dbuf

    const int tid   = threadIdx.x;
    const int bid   = blockIdx.x;
    const int chunk = bid >> 2;
    const int ntile = bid & 3;
    const long k0   = (long)chunk * KC;

    // staging: A: 2 threads/row (16 floats); B: 4 threads/row (8 floats)
    const int a_row = tid >> 1;
    const int a_kh  = (tid & 1) * 8;
    const int b_row = tid >> 2;
    const int b_kh  = (tid & 3) * 4;

    const float4* ap = (const float4*)(Q + (long)a_row * KTOT + k0 + (long)a_kh * 2);
    const float4* bp = (const float4*)(S + (long)(ntile * BN + b_row) * KTOT + k0 + (long)b_kh * 2);

    const int lane = tid & 63;
    const int wave = tid >> 6;
    const int wm = wave >> 1;   // 0..3
    const int wn = wave & 1;    // 0..1
    const int lr = lane & 15;
    const int lk = lane >> 4;

    int aoff[4], boff[4];
#pragma unroll
    for (int f = 0; f < 4; ++f) {
        aoff[f] = (wm * 64 + f * 16 + lr) * LSTRIDE + lk * 4;
        boff[f] = (wn * 64 + f * 16 + lr) * LSTRIDE + lk * 4;
    }

    f32x4 acc[4][4];
#pragma unroll
    for (int i = 0; i < 4; ++i)
#pragma unroll
        for (int j = 0; j < 4; ++j)
            acc[i][j] = (f32x4){0.f, 0.f, 0.f, 0.f};

    float ssq = 0.f;
    const int awr = a_row * LSTRIDE + a_kh;
    const int bwr = b_row * LSTRIDE + b_kh;

    unsigned int* buf0 = Lds;
    unsigned int* buf1 = Lds + HALF;

    // two named prefetch slots
    float4 Aa0, Aa1, Aa2, Aa3, Ab0, Ab1;   // slot A
    float4 Ba0, Ba1, Ba2, Ba3, Bb0, Bb1;   // slot B

    // prologue: tiles 0,1 loaded; tile 0 split into buf0; slot A reloads tile 2
    LOADSLOT(Aa0, Aa1, Aa2, Aa3, Ab0, Ab1, 0)
    LOADSLOT(Ba0, Ba1, Ba2, Ba3, Bb0, Bb1, 1)
    split_store(buf0, Aa0, Aa1, Aa2, Aa3, Ab0, Ab1, awr, bwr, ssq);      // tile 0
    LOADSLOT(Aa0, Aa1, Aa2, Aa3, Ab0, Ab1, 2)
    __syncthreads();

    for (int s = 0; s < NSTEPS - 2; s += 2) {
        // even body: buf0 = tile s; slot B = tile s+1; slot A = tile s+2 (in flight)
        split_store(buf1, Ba0, Ba1, Ba2, Ba3, Bb0, Bb1, awr, bwr, ssq);  // tile s+1
        LOADSLOT(Ba0, Ba1, Ba2, Ba3, Bb0, Bb1, s + 3)
        mfma_phase(buf0, aoff, boff, acc);                               // tile s
        __syncthreads();
        // odd body: buf1 = tile s+1; slot A = tile s+2
        split_store(buf0, Aa0, Aa1, Aa2, Aa3, Ab0, Ab1, awr, bwr, ssq);  // tile s+2
        {
            int ls = s + 4; if (ls > NSTEPS - 1) ls = NSTEPS - 1;        // tail clamp
            LOADSLOT(Aa0, Aa1, Aa2, Aa3, Ab0, Ab1, ls)
        }
        mfma_phase(buf1, aoff, boff, acc);                               // tile s+1
        __syncthreads();
    }
    // epilogue: buf0 = tile 126; slot B = tile 127
    split_store(buf1, Ba0, Ba1, Ba2, Ba3, Bb0, Bb1, awr, bwr, ssq);      // tile 127
    mfma_phase(buf0, aoff, boff, acc);                                   // tile 126
    __syncthreads();
    mfma_phase(buf1, aoff, boff, acc);                                   // tile 127

    // s2 partials: reduce the 4 stager lanes of each B row
    float s1 = ssq + __shfl_xor(ssq, 1);
    float s2v = s1 + __shfl_xor(s1, 2);
    if ((tid & 3) == 0) s2part[chunk * NS + ntile * BN + b_row] = s2v;

    // write q.s partial tile  (C/D layout: col=lane&15, row=(lane>>4)*4+reg)
    float* op = Ppart + (long)chunk * (MQ * NS);
#pragma unroll
    for (int i = 0; i < 4; ++i)
#pragma unroll
        for (int j = 0; j < 4; ++j) {
            int mb = wm * 64 + i * 16 + lk * 4;
            int nn = ntile * BN + wn * 64 + j * 16 + lr;
#pragma unroll
            for (int r = 0; r < 4; ++r)
                op[(long)(mb + r) * NS + nn] = acc[i][j][r];
        }
}

// ---------------------------------------------------------------------------
// K2: one block per query row: reduce K-split partials -> d2 row -> top-10
// ---------------------------------------------------------------------------
__global__ __launch_bounds__(256)
void k2_topk(const float* __restrict__ Ppart, const float* __restrict__ s2part,
             int* __restrict__ idxb)
{
    __shared__ float d2s[NS];
    const int m = blockIdx.x;
    const int tid = threadIdx.x;
    for (int nn = tid; nn < NS; nn += 256) {
        float s2 = 0.f, p = 0.f;
        for (int c = 0; c < KSPLIT; ++c) {
            s2 += s2part[c * NS + nn];
            p  += Ppart[(long)c * (MQ * NS) + (long)m * NS + nn];
        }
        d2s[nn] = s2 - 2.f * p;
    }
    __syncthreads();
    if (tid < 64) {
        unsigned long long key[8];
#pragma unroll
        for (int j = 0; j < 8; ++j) {
            int n = tid * 8 + j;
            unsigned int u = __float_as_uint(d2s[n]);
            u = (u >> 31) ? ~u : (u | 0x80000000u);   // total order, ascending
            key[j] = ((unsigned long long)u << 32) | (unsigned int)n;
        }
        for (int it = 0; it < 10; ++it) {
            unsigned long long best = key[0];
#pragma unroll
            for (int j = 1; j < 8; ++j) best = key[j] < best ? key[j] : best;
            for (int d = 1; d < 64; d <<= 1) {
                unsigned long long o = __shfl_xor(best, d);
                best = o < best ? o : best;
            }
            if (tid == 0) idxb[m * 10 + it] = (int)(best & 0xFFFFFFFFu);
#pragma unroll
            for (int j = 0; j < 8; ++j) if (key[j] == best) key[j] = ~0ull;
        }
    }
}

// ---------------------------------------------------------------------------
// K3: losses / best_k / threshold / mask  (integer sums < 2^24 -> exact fp32)
// ---------------------------------------------------------------------------
__global__ __launch_bounds__(256)
void k3_thresh(const int* __restrict__ idxb, float* __restrict__ mask)
{
    __shared__ int colsum[10];
    __shared__ float thr;
    const int tid = threadIdx.x;
    if (tid < 10) {
        int s = 0;
        for (int m = 0; m < MQ; ++m) s += idxb[m * 10 + tid];
        colsum[tid] = s;
    }
    __syncthreads();
    if (tid == 0) {
        float pre = 0.f, best = 3.4e38f;
        for (int k = 1; k <= 10; ++k) {
            pre += (float)colsum[k - 1];
            float loss = pre / (256.0f * (float)k);
            if (loss < best) best = loss;   // first-min == argmin; threshold = losses[best_k]
        }
        thr = best;
    }
    __syncthreads();
    if (tid < MQ) mask[tid] = ((float)idxb[tid * 10] < thr) ? 1.0f : 0.0f;
}

// ---------------------------------------------------------------------------
// K4: out = q * mask[row]   (float4, 2^18 floats per row)
// ---------------------------------------------------------------------------
__global__ __launch_bounds__(256)
void k4_apply(const float* __restrict__ Q, const float* __restrict__ mask,
              float* __restrict__ out)
{
    long i = ((long)blockIdx.x * 256 + threadIdx.x) * 4;
    int row = (int)(i >> 18);
    float4 v = *(const float4*)(Q + i);
    float mm = mask[row];
    v.x *= mm; v.y *= mm; v.z *= mm; v.w *= mm;
    *(float4*)(out + i) = v;
}

extern "C" void kernel_launch(void* const* d_in, const int* in_sizes, int n_in,
                              void* d_out, int out_size, void* d_ws, size_t ws_size,
                              hipStream_t stream)
{
    const float* Q = (const float*)d_in[0];
    const float* S = (const float*)d_in[1];
    float* out = (float*)d_out;

    // scratch inside d_out (overwritten by k4 afterwards); only mask must
    // survive into k4, so it lives in d_ws.
    float* Ppart  = out;                                   // 64*256*512 f32 = 32 MiB
    float* s2part = out + (long)KSPLIT * MQ * NS;          // 64*512 f32
    int*   idxb   = (int*)(s2part + KSPLIT * NS);          // 256*10 int
    float* mask   = (float*)d_ws;                          // 256 f32

    hipLaunchKernelGGL(k1_gemm,  dim3(KSPLIT * 4), dim3(512), 0, stream, Q, S, Ppart, s2part);
    hipLaunchKernelGGL(k2_topk,  dim3(MQ),         dim3(256), 0, stream, Ppart, s2part, idxb);
    hipLaunchKernelGGL(k3_thresh,dim3(1),          dim3(256), 0, stream, idxb, mask);
    hipLaunchKernelGGL(k4_apply, dim3(65536),      dim3(256), 0, stream, Q, mask, out);
}